// Round 4
// baseline (427.270 us; speedup 1.0000x reference)
//
#include <hip/hip_runtime.h>

typedef unsigned short ushort_t;
typedef __attribute__((ext_vector_type(8))) short short8;
typedef __attribute__((ext_vector_type(4))) float float4v;
typedef __attribute__((ext_vector_type(4))) ushort_t ushort4v;

#define B_ROWS 8192
#define HDIM   1024
#define GLD    5120   // G cols: [hat(c) | hat_raw | r | z | xh]

__device__ __forceinline__ float bf2f(ushort_t u) {
    return __uint_as_float(((unsigned)u) << 16);
}
__device__ __forceinline__ ushort_t f2bf(float f) {
    unsigned u = __float_as_uint(f);
    u += 0x7FFFu + ((u >> 16) & 1u);   // round-to-nearest-even
    return (ushort_t)(u >> 16);
}

// ---- one pack kernel for A, W, Whh ----------------------------------------
// grid.x = 16384 (A: 8192x2048) + 10240 (W: 5120x2048) + 1024 (Whh: 1024x1024)
__global__ __launch_bounds__(256) void pack_all(
    const float* __restrict__ x, const float* __restrict__ h,
    const float* __restrict__ wc, const float* __restrict__ what,
    const float* __restrict__ wxr, const float* __restrict__ whr,
    const float* __restrict__ wxz, const float* __restrict__ whz,
    const float* __restrict__ wxh, const float* __restrict__ whh,
    ushort_t* __restrict__ A, ushort_t* __restrict__ W,
    ushort_t* __restrict__ Whh)
{
    const int bid = blockIdx.x;
    float4v v;
    ushort_t* dst;
    size_t i4;
    if (bid < 16384) {                       // ---- A = [x | hidden]
        i4 = ((size_t)bid * 256 + threadIdx.x) * 4;
        int c = (int)(i4 & 2047);
        size_t b = i4 >> 11;
        const float* src = (c < 1024) ? (x + b * 1024 + c)
                                      : (h + b * 1024 + (c - 1024));
        v = *(const float4v*)src;
        dst = A + i4;
    } else if (bid < 26624) {                // ---- W rows: wc|what|[xr|hr]|[xz|hz]|[xh|junk]
        i4 = ((size_t)(bid - 16384) * 256 + threadIdx.x) * 4;
        int j = (int)(i4 >> 11);
        int k = (int)(i4 & 2047);
        int r = j >> 10, jr = j & 1023;
        if (r == 0) {
            v = *(const float4v*)(wc + (size_t)j * 2048 + k);
        } else if (r == 1) {
            v = *(const float4v*)(what + (size_t)jr * 2048 + k);
        } else if (r == 4) {
            // K=1024 for this region in the GEMM; k>=1024 never read
            v = (k < 1024) ? *(const float4v*)(wxh + (size_t)jr * 1024 + k)
                           : (float4v){0.f, 0.f, 0.f, 0.f};
        } else {
            const float* p0 = (r == 2) ? wxr : wxz;
            const float* p1 = (r == 2) ? whr : whz;
            const float* p = (k < 1024) ? (p0 + (size_t)jr * 1024 + k)
                                        : (p1 + (size_t)jr * 1024 + (k - 1024));
            v = *(const float4v*)p;
        }
        dst = W + i4;
    } else {                                 // ---- Whh
        i4 = ((size_t)(bid - 26624) * 256 + threadIdx.x) * 4;
        v = *(const float4v*)(whh + i4);
        dst = Whh + i4;
    }
    ushort4v o;
#pragma unroll
    for (int t = 0; t < 4; ++t) o[t] = f2bf(v[t]);
    *(ushort4v*)dst = o;
}

// ---- GEMM1: G = A @ W^T, bf16 out, 256x128 tile ----------------------------
// 4 waves, each computes 64 rows x 128 cols (acc 4x8). BK=32.
// Per K-step: 24 global_load_lds w=16 (6/wave), 12 ds_read_b128, 32 MFMA.
__global__ __launch_bounds__(256, 2) void gemm1(
    const ushort_t* __restrict__ A, const ushort_t* __restrict__ B,
    ushort_t* __restrict__ C)
{
    const int bn0 = blockIdx.x * 128;
    const int bm0 = blockIdx.y * 256;
    const int K = (bn0 >= 4096) ? 1024 : 2048;   // xh region has K=1024

    __shared__ ushort_t As[256 * 32];   // 16 KiB
    __shared__ ushort_t Bs[128 * 32];   //  8 KiB

    const int t = threadIdx.x;
    const int wave = t >> 6, lane = t & 63;
    const int q = lane >> 4, r16 = lane & 15;
    const int lrow = lane >> 2;          // 0..15
    const int lcol = (lane & 3) * 8;     // 0,8,16,24

    float4v acc[4][8];
#pragma unroll
    for (int i = 0; i < 4; ++i)
#pragma unroll
        for (int j = 0; j < 8; ++j)
            acc[i][j] = {0.f, 0.f, 0.f, 0.f};

    for (int k0 = 0; k0 < K; k0 += 32) {
        // stage: 24 chunks of 16 rows (A: 0..15, B: 16..23), 6 per wave
#pragma unroll
        for (int j = 0; j < 6; ++j) {
            int l = wave * 6 + j;
            if (l < 16) {
                const ushort_t* gp = A + (size_t)(bm0 + l * 16 + lrow) * 2048 + k0 + lcol;
                __builtin_amdgcn_global_load_lds(
                    (const __attribute__((address_space(1))) void*)gp,
                    (__attribute__((address_space(3))) void*)(As + l * 512),
                    16, 0, 0);
            } else {
                const ushort_t* gp = B + (size_t)(bn0 + (l - 16) * 16 + lrow) * 2048 + k0 + lcol;
                __builtin_amdgcn_global_load_lds(
                    (const __attribute__((address_space(1))) void*)gp,
                    (__attribute__((address_space(3))) void*)(Bs + (l - 16) * 512),
                    16, 0, 0);
            }
        }
        __syncthreads();

        short8 af[4], bf[8];
#pragma unroll
        for (int mi = 0; mi < 4; ++mi)
            af[mi] = *(const short8*)&As[(wave * 64 + mi * 16 + r16) * 32 + q * 8];
#pragma unroll
        for (int ni = 0; ni < 8; ++ni)
            bf[ni] = *(const short8*)&Bs[(ni * 16 + r16) * 32 + q * 8];
#pragma unroll
        for (int mi = 0; mi < 4; ++mi)
#pragma unroll
            for (int ni = 0; ni < 8; ++ni)
                acc[mi][ni] = __builtin_amdgcn_mfma_f32_16x16x32_bf16(
                    af[mi], bf[ni], acc[mi][ni], 0, 0, 0);
        __syncthreads();
    }

    // C/D layout: col = lane&15, row = (lane>>4)*4 + reg  [m89/m91]
#pragma unroll
    for (int mi = 0; mi < 4; ++mi)
#pragma unroll
        for (int ni = 0; ni < 8; ++ni)
#pragma unroll
            for (int reg = 0; reg < 4; ++reg) {
                int row = bm0 + wave * 64 + mi * 16 + q * 4 + reg;
                int col = bn0 + ni * 16 + r16;
                C[(size_t)row * GLD + col] = f2bf(acc[mi][ni][reg]);
            }
}

// ---- fused row pass: softmax*relu (hat) + rh, wave-per-row, no syncs -------
__global__ __launch_bounds__(256) void row_pass(
    ushort_t* __restrict__ G, const float* __restrict__ bias_c,
    const float* __restrict__ bias_hat, const float* __restrict__ bias_r,
    const float* __restrict__ hidden, ushort_t* __restrict__ rh)
{
    const int wave = threadIdx.x >> 6, lane = threadIdx.x & 63;
    const size_t row = (size_t)blockIdx.x * 4 + wave;
    ushort_t* g = G + row * GLD;
    const int c0 = lane * 16;

    float cv[16];
    {
        short8 a = *(const short8*)(g + c0);
        short8 b = *(const short8*)(g + c0 + 8);
#pragma unroll
        for (int i = 0; i < 8; ++i) {
            cv[i]     = bf2f((ushort_t)a[i]) + bias_c[c0 + i];
            cv[8 + i] = bf2f((ushort_t)b[i]) + bias_c[c0 + 8 + i];
        }
    }
    float mx = cv[0];
#pragma unroll
    for (int i = 1; i < 16; ++i) mx = fmaxf(mx, cv[i]);
#pragma unroll
    for (int m = 1; m < 64; m <<= 1) mx = fmaxf(mx, __shfl_xor(mx, m));
    float sum = 0.f;
#pragma unroll
    for (int i = 0; i < 16; ++i) { cv[i] = __expf(cv[i] - mx); sum += cv[i]; }
#pragma unroll
    for (int m = 1; m < 64; m <<= 1) sum += __shfl_xor(sum, m);
    const float inv = 1.0f / sum;

    {
        short8 a = *(const short8*)(g + 1024 + c0);
        short8 b = *(const short8*)(g + 1024 + c0 + 8);
        short8 oa, ob;
#pragma unroll
        for (int i = 0; i < 8; ++i) {
            float ha = bf2f((ushort_t)a[i]) + bias_hat[c0 + i];
            float hb = bf2f((ushort_t)b[i]) + bias_hat[c0 + 8 + i];
            oa[i] = (short)f2bf(cv[i] * inv * fmaxf(ha, 0.f));
            ob[i] = (short)f2bf(cv[8 + i] * inv * fmaxf(hb, 0.f));
        }
        *(short8*)(g + c0) = oa;
        *(short8*)(g + c0 + 8) = ob;
    }

    {
        short8 a = *(const short8*)(g + 2048 + c0);
        short8 b = *(const short8*)(g + 2048 + c0 + 8);
        const float* hp = hidden + row * 1024 + c0;
        short8 oa, ob;
#pragma unroll
        for (int i = 0; i < 8; ++i) {
            float ra = 1.0f / (1.0f + __expf(-(bf2f((ushort_t)a[i]) + bias_r[c0 + i])));
            float rb = 1.0f / (1.0f + __expf(-(bf2f((ushort_t)b[i]) + bias_r[c0 + 8 + i])));
            oa[i] = (short)f2bf(ra * hp[i]);
            ob[i] = (short)f2bf(rb * hp[8 + i]);
        }
        ushort_t* rp = rh + row * 1024 + c0;
        *(short8*)rp = oa;
        *(short8*)(rp + 8) = ob;
    }
}

// ---- GEMM2 with fused final epilogue (LDS-staged, coalesced) ---------------
// t6 = rh @ Whh^T; out = (1-z)*tanh(xh + bias_h + t6) + z*hidden + hat
#define CSTRIDE 132   // 128 + 4: quad-row groups land on distinct bank octets
__global__ __launch_bounds__(256) void gemm2_final(
    const ushort_t* __restrict__ A, const ushort_t* __restrict__ B,
    const ushort_t* __restrict__ G, const float* __restrict__ bias_z,
    const float* __restrict__ bias_h, const float* __restrict__ hidden,
    float* __restrict__ out)
{
    const int bn0 = blockIdx.x * 128;
    const int bm0 = blockIdx.y * 128;

    __shared__ ushort_t smem[128 * CSTRIDE];   // 33 KiB; loop uses first 16 KiB
    ushort_t* As = smem;
    ushort_t* Bs = smem + 4096;

    const int t = threadIdx.x;
    const int wave = t >> 6, lane = t & 63;
    const int wr = wave >> 1, wcq = wave & 1;
    const int q = lane >> 4, r16 = lane & 15;
    const int lrow = lane >> 2;
    const int lcol = (lane & 3) * 8;

    float4v acc[4][4];
#pragma unroll
    for (int i = 0; i < 4; ++i)
#pragma unroll
        for (int j = 0; j < 4; ++j)
            acc[i][j] = {0.f, 0.f, 0.f, 0.f};

    for (int k0 = 0; k0 < 1024; k0 += 32) {
        if (wave < 2) {
#pragma unroll
            for (int j = 0; j < 4; ++j) {
                int c = wave * 4 + j;
                const ushort_t* gp = A + (size_t)(bm0 + c * 16 + lrow) * 1024 + k0 + lcol;
                __builtin_amdgcn_global_load_lds(
                    (const __attribute__((address_space(1))) void*)gp,
                    (__attribute__((address_space(3))) void*)(As + c * 512),
                    16, 0, 0);
            }
        } else {
#pragma unroll
            for (int j = 0; j < 4; ++j) {
                int c = (wave - 2) * 4 + j;
                const ushort_t* gp = B + (size_t)(bn0 + c * 16 + lrow) * 1024 + k0 + lcol;
                __builtin_amdgcn_global_load_lds(
                    (const __attribute__((address_space(1))) void*)gp,
                    (__attribute__((address_space(3))) void*)(Bs + c * 512),
                    16, 0, 0);
            }
        }
        __syncthreads();

        short8 af[4], bf[4];
#pragma unroll
        for (int mi = 0; mi < 4; ++mi)
            af[mi] = *(const short8*)&As[(wr * 64 + mi * 16 + r16) * 32 + q * 8];
#pragma unroll
        for (int ni = 0; ni < 4; ++ni)
            bf[ni] = *(const short8*)&Bs[(wcq * 64 + ni * 16 + r16) * 32 + q * 8];
#pragma unroll
        for (int mi = 0; mi < 4; ++mi)
#pragma unroll
            for (int ni = 0; ni < 4; ++ni)
                acc[mi][ni] = __builtin_amdgcn_mfma_f32_16x16x32_bf16(
                    af[mi], bf[ni], acc[mi][ni], 0, 0, 0);
        __syncthreads();
    }

    // stage t6 tile to LDS (bf16), then coalesced epilogue passes
#pragma unroll
    for (int mi = 0; mi < 4; ++mi)
#pragma unroll
        for (int ni = 0; ni < 4; ++ni)
#pragma unroll
            for (int reg = 0; reg < 4; ++reg) {
                int rl = wr * 64 + mi * 16 + q * 4 + reg;
                int cl = wcq * 64 + ni * 16 + r16;
                smem[rl * CSTRIDE + cl] = f2bf(acc[mi][ni][reg]);
            }
    __syncthreads();

    const int colL = t & 127;
    const int gc = bn0 + colL;
    const float bz = bias_z[gc];
    const float bh = bias_h[gc];
    const int rbase = t >> 7;                  // 0 or 1
#pragma unroll 4
    for (int pass = 0; pass < 64; ++pass) {
        const int rowL = pass * 2 + rbase;
        const size_t gr = (size_t)(bm0 + rowL);
        const ushort_t* grow = G + gr * GLD;
        float z = 1.0f / (1.0f + __expf(-(bf2f(grow[3072 + gc]) + bz)));
        float targ = bf2f(grow[4096 + gc]) + bh + bf2f(smem[rowL * CSTRIDE + colL]);
        float th = 1.0f - 2.0f / (__expf(2.0f * targ) + 1.0f);
        out[gr * 1024 + gc] =
            (1.0f - z) * th + z * hidden[gr * 1024 + gc] + bf2f(grow[gc]);
    }
}

// ---- launch ----------------------------------------------------------------

extern "C" void kernel_launch(void* const* d_in, const int* in_sizes, int n_in,
                              void* d_out, int out_size, void* d_ws, size_t ws_size,
                              hipStream_t stream)
{
    const float* x        = (const float*)d_in[0];
    const float* hidden   = (const float*)d_in[1];
    const float* wxr      = (const float*)d_in[2];
    const float* whr      = (const float*)d_in[3];
    const float* bias_r   = (const float*)d_in[4];
    const float* wxz      = (const float*)d_in[5];
    const float* whz      = (const float*)d_in[6];
    const float* bias_z   = (const float*)d_in[7];
    const float* wxh      = (const float*)d_in[8];
    const float* whh      = (const float*)d_in[9];
    const float* bias_h   = (const float*)d_in[10];
    const float* wc       = (const float*)d_in[11];
    const float* bias_c   = (const float*)d_in[12];
    const float* what     = (const float*)d_in[13];
    const float* bias_hat = (const float*)d_in[14];
    float* out = (float*)d_out;

    char* ws = (char*)d_ws;
    ushort_t* G     = (ushort_t*)(ws);                    // [8192,5120] bf16, 80 MiB
    ushort_t* Abf   = (ushort_t*)(ws + 83886080);         // [8192,2048] bf16, 32 MiB
    ushort_t* Wbf   = (ushort_t*)(ws + 117440512);        // [5120,2048] bf16, 20 MiB
    ushort_t* Whhbf = (ushort_t*)(ws + 138412032);        // [1024,1024] bf16,  2 MiB
    ushort_t* rhbf  = (ushort_t*)(ws + 140509184);        // [8192,1024] bf16, 16 MiB

    pack_all<<<27648, 256, 0, stream>>>(x, hidden, wc, what, wxr, whr, wxz, whz,
                                        wxh, whh, Abf, Wbf, Whhbf);

    // GEMM1: G = Abf @ Wbf^T   (M=8192, N=5120, K=2048; xh region K=1024)
    gemm1<<<dim3(40, 32), 256, 0, stream>>>(Abf, Wbf, G);

    // fused softmax/hat + rh (wave per row)
    row_pass<<<B_ROWS / 4, 256, 0, stream>>>(G, bias_c, bias_hat, bias_r, hidden, rhbf);

    // GEMM2 + final epilogue -> out
    gemm2_final<<<dim3(8, 64), 256, 0, stream>>>(rhbf, Whhbf, G, bias_z, bias_h,
                                                 hidden, out);
}

// Round 5
// 376.348 us; speedup vs baseline: 1.1353x; 1.1353x over previous
//
#include <hip/hip_runtime.h>

typedef unsigned short ushort_t;
typedef __attribute__((ext_vector_type(8))) short short8;
typedef __attribute__((ext_vector_type(4))) float float4v;
typedef __attribute__((ext_vector_type(4))) ushort_t ushort4v;

#define B_ROWS 8192
#define HDIM   1024
#define GLD    5120   // G cols: [hat(c) | hat_raw | r | z | xh]

__device__ __forceinline__ float bf2f(ushort_t u) {
    return __uint_as_float(((unsigned)u) << 16);
}
__device__ __forceinline__ ushort_t f2bf(float f) {
    unsigned u = __float_as_uint(f);
    u += 0x7FFFu + ((u >> 16) & 1u);   // round-to-nearest-even
    return (ushort_t)(u >> 16);
}

// ---- one pack kernel for A, W, Whh ----------------------------------------
__global__ __launch_bounds__(256) void pack_all(
    const float* __restrict__ x, const float* __restrict__ h,
    const float* __restrict__ wc, const float* __restrict__ what,
    const float* __restrict__ wxr, const float* __restrict__ whr,
    const float* __restrict__ wxz, const float* __restrict__ whz,
    const float* __restrict__ wxh, const float* __restrict__ whh,
    ushort_t* __restrict__ A, ushort_t* __restrict__ W,
    ushort_t* __restrict__ Whh)
{
    const int bid = blockIdx.x;
    float4v v;
    ushort_t* dst;
    size_t i4;
    if (bid < 16384) {                       // ---- A = [x | hidden]
        i4 = ((size_t)bid * 256 + threadIdx.x) * 4;
        int c = (int)(i4 & 2047);
        size_t b = i4 >> 11;
        const float* src = (c < 1024) ? (x + b * 1024 + c)
                                      : (h + b * 1024 + (c - 1024));
        v = *(const float4v*)src;
        dst = A + i4;
    } else if (bid < 26624) {                // ---- W rows: wc|what|[xr|hr]|[xz|hz]|[xh|junk]
        i4 = ((size_t)(bid - 16384) * 256 + threadIdx.x) * 4;
        int j = (int)(i4 >> 11);
        int k = (int)(i4 & 2047);
        int r = j >> 10, jr = j & 1023;
        if (r == 0) {
            v = *(const float4v*)(wc + (size_t)j * 2048 + k);
        } else if (r == 1) {
            v = *(const float4v*)(what + (size_t)jr * 2048 + k);
        } else if (r == 4) {
            v = (k < 1024) ? *(const float4v*)(wxh + (size_t)jr * 1024 + k)
                           : (float4v){0.f, 0.f, 0.f, 0.f};
        } else {
            const float* p0 = (r == 2) ? wxr : wxz;
            const float* p1 = (r == 2) ? whr : whz;
            const float* p = (k < 1024) ? (p0 + (size_t)jr * 1024 + k)
                                        : (p1 + (size_t)jr * 1024 + (k - 1024));
            v = *(const float4v*)p;
        }
        dst = W + i4;
    } else {                                 // ---- Whh
        i4 = ((size_t)(bid - 26624) * 256 + threadIdx.x) * 4;
        v = *(const float4v*)(whh + i4);
        dst = Whh + i4;
    }
    ushort4v o;
#pragma unroll
    for (int t = 0; t < 4; ++t) o[t] = f2bf(v[t]);
    *(ushort4v*)dst = o;
}

// ---- GEMM1: G = A @ W^T, 256x128 tile, BK=64, XOR-swizzled LDS -------------
// 16 barrier-drains for K=2048 (vs 32 at BK=32). LDS rows are 128B; swizzle:
// LDS chunk c of row r holds global k-chunk c^(r&7)  (chunk = 8 bf16 = 16B).
__global__ __launch_bounds__(256, 2) void gemm1(
    const ushort_t* __restrict__ A, const ushort_t* __restrict__ B,
    ushort_t* __restrict__ C)
{
    const int bn0 = blockIdx.x * 128;
    const int bm0 = blockIdx.y * 256;
    const int K = (bn0 >= 4096) ? 1024 : 2048;   // xh region has K=1024

    __shared__ ushort_t As[256 * 64];   // 32 KiB
    __shared__ ushort_t Bs[128 * 64];   // 16 KiB

    const int t = threadIdx.x;
    const int wave = t >> 6, lane = t & 63;
    const int q = lane >> 4, r16 = lane & 15;
    const int lrow8 = lane >> 3;                 // 0..7 (8 rows per load instr)
    const int kswz = ((lane & 7) ^ lrow8) * 8;   // swizzled global k-offset
    const int xm = (r16 & 7);                    // per-lane xor mask for ds_read

    float4v acc[4][8];
#pragma unroll
    for (int i = 0; i < 4; ++i)
#pragma unroll
        for (int j = 0; j < 8; ++j)
            acc[i][j] = {0.f, 0.f, 0.f, 0.f};

    for (int k0 = 0; k0 < K; k0 += 64) {
        // A: 32 chunks of 8 rows, 8 per wave; B: 16 chunks, 4 per wave
#pragma unroll
        for (int j = 0; j < 8; ++j) {
            int l = wave * 8 + j;
            const ushort_t* gp = A + (size_t)(bm0 + l * 8 + lrow8) * 2048 + k0 + kswz;
            __builtin_amdgcn_global_load_lds(
                (const __attribute__((address_space(1))) void*)gp,
                (__attribute__((address_space(3))) void*)(As + l * 512),
                16, 0, 0);
        }
#pragma unroll
        for (int j = 0; j < 4; ++j) {
            int l = wave * 4 + j;
            const ushort_t* gp = B + (size_t)(bn0 + l * 8 + lrow8) * 2048 + k0 + kswz;
            __builtin_amdgcn_global_load_lds(
                (const __attribute__((address_space(1))) void*)gp,
                (__attribute__((address_space(3))) void*)(Bs + l * 512),
                16, 0, 0);
        }
        __syncthreads();

#pragma unroll
        for (int kh = 0; kh < 2; ++kh) {
            short8 af[4];
#pragma unroll
            for (int mi = 0; mi < 4; ++mi)
                af[mi] = *(const short8*)
                    &As[(wave * 64 + mi * 16 + r16) * 64 + (((kh * 4 + q) ^ xm) * 8)];
#pragma unroll
            for (int ni = 0; ni < 8; ++ni) {
                short8 bf = *(const short8*)
                    &Bs[(ni * 16 + r16) * 64 + (((kh * 4 + q) ^ xm) * 8)];
#pragma unroll
                for (int mi = 0; mi < 4; ++mi)
                    acc[mi][ni] = __builtin_amdgcn_mfma_f32_16x16x32_bf16(
                        af[mi], bf, acc[mi][ni], 0, 0, 0);
            }
        }
        __syncthreads();
    }

    // C/D layout: col = lane&15, row = (lane>>4)*4 + reg  [m89/m91]
#pragma unroll
    for (int mi = 0; mi < 4; ++mi)
#pragma unroll
        for (int ni = 0; ni < 8; ++ni)
#pragma unroll
            for (int reg = 0; reg < 4; ++reg) {
                int row = bm0 + wave * 64 + mi * 16 + q * 4 + reg;
                int col = bn0 + ni * 16 + r16;
                C[(size_t)row * GLD + col] = f2bf(acc[mi][ni][reg]);
            }
}

// ---- fused row pass: softmax*relu (hat) + rh, wave-per-row, no syncs -------
__global__ __launch_bounds__(256) void row_pass(
    ushort_t* __restrict__ G, const float* __restrict__ bias_c,
    const float* __restrict__ bias_hat, const float* __restrict__ bias_r,
    const float* __restrict__ hidden, ushort_t* __restrict__ rh)
{
    const int wave = threadIdx.x >> 6, lane = threadIdx.x & 63;
    const size_t row = (size_t)blockIdx.x * 4 + wave;
    ushort_t* g = G + row * GLD;
    const int c0 = lane * 16;

    float cv[16];
    {
        short8 a = *(const short8*)(g + c0);
        short8 b = *(const short8*)(g + c0 + 8);
#pragma unroll
        for (int i = 0; i < 8; ++i) {
            cv[i]     = bf2f((ushort_t)a[i]) + bias_c[c0 + i];
            cv[8 + i] = bf2f((ushort_t)b[i]) + bias_c[c0 + 8 + i];
        }
    }
    float mx = cv[0];
#pragma unroll
    for (int i = 1; i < 16; ++i) mx = fmaxf(mx, cv[i]);
#pragma unroll
    for (int m = 1; m < 64; m <<= 1) mx = fmaxf(mx, __shfl_xor(mx, m));
    float sum = 0.f;
#pragma unroll
    for (int i = 0; i < 16; ++i) { cv[i] = __expf(cv[i] - mx); sum += cv[i]; }
#pragma unroll
    for (int m = 1; m < 64; m <<= 1) sum += __shfl_xor(sum, m);
    const float inv = 1.0f / sum;

    {
        short8 a = *(const short8*)(g + 1024 + c0);
        short8 b = *(const short8*)(g + 1024 + c0 + 8);
        short8 oa, ob;
#pragma unroll
        for (int i = 0; i < 8; ++i) {
            float ha = bf2f((ushort_t)a[i]) + bias_hat[c0 + i];
            float hb = bf2f((ushort_t)b[i]) + bias_hat[c0 + 8 + i];
            oa[i] = (short)f2bf(cv[i] * inv * fmaxf(ha, 0.f));
            ob[i] = (short)f2bf(cv[8 + i] * inv * fmaxf(hb, 0.f));
        }
        *(short8*)(g + c0) = oa;
        *(short8*)(g + c0 + 8) = ob;
    }

    {
        short8 a = *(const short8*)(g + 2048 + c0);
        short8 b = *(const short8*)(g + 2048 + c0 + 8);
        const float* hp = hidden + row * 1024 + c0;
        short8 oa, ob;
#pragma unroll
        for (int i = 0; i < 8; ++i) {
            float ra = 1.0f / (1.0f + __expf(-(bf2f((ushort_t)a[i]) + bias_r[c0 + i])));
            float rb = 1.0f / (1.0f + __expf(-(bf2f((ushort_t)b[i]) + bias_r[c0 + 8 + i])));
            oa[i] = (short)f2bf(ra * hp[i]);
            ob[i] = (short)f2bf(rb * hp[8 + i]);
        }
        ushort_t* rp = rh + row * 1024 + c0;
        *(short8*)rp = oa;
        *(short8*)(rp + 8) = ob;
    }
}

// ---- GEMM2 + fused final epilogue, 64x128 tile for TLP ---------------------
// t6 = rh @ Whh^T; out = (1-z)*tanh(xh + bias_h + t6) + z*hidden + hat
#define CSTRIDE 132
__global__ __launch_bounds__(256) void gemm2_final(
    const ushort_t* __restrict__ A, const ushort_t* __restrict__ B,
    const ushort_t* __restrict__ G, const float* __restrict__ bias_z,
    const float* __restrict__ bias_h, const float* __restrict__ hidden,
    float* __restrict__ out)
{
    const int bn0 = blockIdx.x * 128;
    const int bm0 = blockIdx.y * 64;

    __shared__ ushort_t smem[64 * CSTRIDE];   // 16.5 KiB; K-loop uses first 12 KiB
    ushort_t* As = smem;            // 64 x 32
    ushort_t* Bs = smem + 2048;     // 128 x 32

    const int t = threadIdx.x;
    const int wave = t >> 6, lane = t & 63;
    const int wr = wave >> 1, wcq = wave & 1;    // 2x2 wave grid: 32m x 64n each
    const int q = lane >> 4, r16 = lane & 15;
    const int lrow = lane >> 2;
    const int lcol = (lane & 3) * 8;

    float4v acc[2][4];
#pragma unroll
    for (int i = 0; i < 2; ++i)
#pragma unroll
        for (int j = 0; j < 4; ++j)
            acc[i][j] = {0.f, 0.f, 0.f, 0.f};

    for (int k0 = 0; k0 < 1024; k0 += 32) {
        // 12 chunks of 16 rows (A: 0..3, B: 4..11), 3 per wave
#pragma unroll
        for (int j = 0; j < 3; ++j) {
            int l = wave * 3 + j;
            if (l < 4) {
                const ushort_t* gp = A + (size_t)(bm0 + l * 16 + lrow) * 1024 + k0 + lcol;
                __builtin_amdgcn_global_load_lds(
                    (const __attribute__((address_space(1))) void*)gp,
                    (__attribute__((address_space(3))) void*)(As + l * 512),
                    16, 0, 0);
            } else {
                const ushort_t* gp = B + (size_t)(bn0 + (l - 4) * 16 + lrow) * 1024 + k0 + lcol;
                __builtin_amdgcn_global_load_lds(
                    (const __attribute__((address_space(1))) void*)gp,
                    (__attribute__((address_space(3))) void*)(Bs + (l - 4) * 512),
                    16, 0, 0);
            }
        }
        __syncthreads();

        short8 af[2], bf[4];
#pragma unroll
        for (int mi = 0; mi < 2; ++mi)
            af[mi] = *(const short8*)&As[(wr * 32 + mi * 16 + r16) * 32 + q * 8];
#pragma unroll
        for (int ni = 0; ni < 4; ++ni)
            bf[ni] = *(const short8*)&Bs[(wcq * 64 + ni * 16 + r16) * 32 + q * 8];
#pragma unroll
        for (int mi = 0; mi < 2; ++mi)
#pragma unroll
            for (int ni = 0; ni < 4; ++ni)
                acc[mi][ni] = __builtin_amdgcn_mfma_f32_16x16x32_bf16(
                    af[mi], bf[ni], acc[mi][ni], 0, 0, 0);
        __syncthreads();
    }

    // stage t6 tile to LDS (bf16), then coalesced epilogue
#pragma unroll
    for (int mi = 0; mi < 2; ++mi)
#pragma unroll
        for (int ni = 0; ni < 4; ++ni)
#pragma unroll
            for (int reg = 0; reg < 4; ++reg) {
                int rl = wr * 32 + mi * 16 + q * 4 + reg;
                int cl = wcq * 64 + ni * 16 + r16;
                smem[rl * CSTRIDE + cl] = f2bf(acc[mi][ni][reg]);
            }
    __syncthreads();

    const int colL = t & 127;
    const int gc = bn0 + colL;
    const float bz = bias_z[gc];
    const float bh = bias_h[gc];
    const int rbase = t >> 7;                  // 0 or 1
#pragma unroll 4
    for (int pass = 0; pass < 32; ++pass) {
        const int rowL = pass * 2 + rbase;
        const size_t gr = (size_t)(bm0 + rowL);
        const ushort_t* grow = G + gr * GLD;
        float z = 1.0f / (1.0f + __expf(-(bf2f(grow[3072 + gc]) + bz)));
        float targ = bf2f(grow[4096 + gc]) + bh + bf2f(smem[rowL * CSTRIDE + colL]);
        float th = 1.0f - 2.0f / (__expf(2.0f * targ) + 1.0f);
        out[gr * 1024 + gc] =
            (1.0f - z) * th + z * hidden[gr * 1024 + gc] + bf2f(grow[gc]);
    }
}

// ---- launch ----------------------------------------------------------------

extern "C" void kernel_launch(void* const* d_in, const int* in_sizes, int n_in,
                              void* d_out, int out_size, void* d_ws, size_t ws_size,
                              hipStream_t stream)
{
    const float* x        = (const float*)d_in[0];
    const float* hidden   = (const float*)d_in[1];
    const float* wxr      = (const float*)d_in[2];
    const float* whr      = (const float*)d_in[3];
    const float* bias_r   = (const float*)d_in[4];
    const float* wxz      = (const float*)d_in[5];
    const float* whz      = (const float*)d_in[6];
    const float* bias_z   = (const float*)d_in[7];
    const float* wxh      = (const float*)d_in[8];
    const float* whh      = (const float*)d_in[9];
    const float* bias_h   = (const float*)d_in[10];
    const float* wc       = (const float*)d_in[11];
    const float* bias_c   = (const float*)d_in[12];
    const float* what     = (const float*)d_in[13];
    const float* bias_hat = (const float*)d_in[14];
    float* out = (float*)d_out;

    char* ws = (char*)d_ws;
    ushort_t* G     = (ushort_t*)(ws);                    // [8192,5120] bf16, 80 MiB
    ushort_t* Abf   = (ushort_t*)(ws + 83886080);         // [8192,2048] bf16, 32 MiB
    ushort_t* Wbf   = (ushort_t*)(ws + 117440512);        // [5120,2048] bf16, 20 MiB
    ushort_t* Whhbf = (ushort_t*)(ws + 138412032);        // [1024,1024] bf16,  2 MiB
    ushort_t* rhbf  = (ushort_t*)(ws + 140509184);        // [8192,1024] bf16, 16 MiB

    pack_all<<<27648, 256, 0, stream>>>(x, hidden, wc, what, wxr, whr, wxz, whz,
                                        wxh, whh, Abf, Wbf, Whhbf);

    // GEMM1: G = Abf @ Wbf^T   (M=8192, N=5120, K=2048; xh region K=1024)
    gemm1<<<dim3(40, 32), 256, 0, stream>>>(Abf, Wbf, G);

    // fused softmax/hat + rh (wave per row)
    row_pass<<<B_ROWS / 4, 256, 0, stream>>>(G, bias_c, bias_hat, bias_r, hidden, rhbf);

    // GEMM2 + final epilogue -> out
    gemm2_final<<<dim3(8, 128), 256, 0, stream>>>(rhbf, Whhbf, G, bias_z, bias_h,
                                                  hidden, out);
}